// Round 5
// baseline (584.962 us; speedup 1.0000x reference)
//
#include <hip/hip_runtime.h>

typedef unsigned short u16;
typedef float f32x4 __attribute__((ext_vector_type(4)));
typedef __bf16 bf16x8 __attribute__((ext_vector_type(8)));

#define T_ 4096
#define D_ 1024
#define NW_ 64

__device__ __forceinline__ float b2f(u16 u) {
  return __uint_as_float(((unsigned)u) << 16);
}
__device__ __forceinline__ u16 f2bf(float f) {
  unsigned u = __float_as_uint(f);
  u += 0x7fffu + ((u >> 16) & 1u);   // RNE
  return (u16)(u >> 16);
}
__device__ __forceinline__ void g2l16(const u16* g, u16* l) {
  __builtin_amdgcn_global_load_lds((const __attribute__((address_space(1))) void*)g,
                                   (__attribute__((address_space(3))) void*)l, 16, 0, 0);
}

// fused fp32->bf16 casts + scores zero-init.
// blocks: [0,16384) x->xb, [16384,19456) Wqkv->wb, [19456,20480) Wcross->wb+3072K,
//         [20480,20496) zero scores (16384 floats)
__global__ __launch_bounds__(256) void cvt3_k(const float* __restrict__ x, u16* __restrict__ xb,
                                              const float* __restrict__ wqkv,
                                              const float* __restrict__ wcross,
                                              u16* __restrict__ wb,
                                              float* __restrict__ scores)
{
  long bid = blockIdx.x;
  if (bid >= 20480) {
    long i = (bid - 20480) * 1024 + (long)threadIdx.x * 4;
    *(float4*)(scores + i) = make_float4(0.f, 0.f, 0.f, 0.f);
    return;
  }
  const float* src; u16* dst; long base;
  if (bid < 16384)      { src = x;      dst = xb;           base = bid * 1024; }
  else if (bid < 19456) { src = wqkv;   dst = wb;           base = (bid - 16384) * 1024; }
  else                  { src = wcross; dst = wb + 3145728; base = (bid - 19456) * 1024; }
  long i = base + (long)threadIdx.x * 4;
  float4 v = *(const float4*)(src + i);
  ushort4 o;
  o.x = f2bf(v.x); o.y = f2bf(v.y); o.z = f2bf(v.z); o.w = f2bf(v.w);
  *(ushort4*)(dst + i) = o;
}

__global__ __launch_bounds__(256) void cvt_k(const float* __restrict__ src,
                                             u16* __restrict__ dst, long n)
{
  long i = ((long)blockIdx.x * 256 + threadIdx.x) * 4;
  if (i >= n) return;
  float4 v = *(const float4*)(src + i);
  ushort4 o;
  o.x = f2bf(v.x); o.y = f2bf(v.y); o.z = f2bf(v.z); o.w = f2bf(v.w);
  *(ushort4*)(dst + i) = o;
}

// Fused x-GEMM: C(16384,4096) = xb @ wb^T. Cols [0,3072) -> qkv (ldc 3072, no bias).
// Cols [3072,4096) -> scores[row] += sum_col tanh(c + bcross[col]) via atomics.
// grid (32,128). XCD swizzle: all col-blocks of a row-block share L%8.
__global__ __launch_bounds__(256) void gemm_x(
    const u16* __restrict__ xb, const u16* __restrict__ wb,
    u16* __restrict__ qkv, float* __restrict__ scores,
    const float* __restrict__ bcross)
{
  __shared__ u16 As[128 * 32];
  __shared__ u16 Bs[128 * 32];
  const int tid = threadIdx.x;
  const int lane = tid & 63;
  const int w = tid >> 6;
  const int wm = w >> 1, wn = w & 1;
  const int q = lane >> 4, il = lane & 15;
  // swizzle: L = bx + by*32; xcd = L&7; k = L>>3; erx = k>>4; ery = xcd + 8*(k&15)
  const int L = blockIdx.x + blockIdx.y * 32;
  const int kk = L >> 3;
  const int erx = kk >> 4;
  const int ery = (L & 7) + ((kk & 15) << 3);
  const long m0 = (long)ery * 128, n0 = (long)erx * 128;
  const int ua = w * 128 + lane;

  f32x4 acc[4][4] = {};

  for (int k0 = 0; k0 < 1024; k0 += 32) {
#pragma unroll
    for (int i = 0; i < 2; ++i) {
      int u = ua + i * 64;
      int row = u >> 2, kp = u & 3;
      g2l16(xb + (m0 + row) * 1024 + k0 + kp * 8, &As[(w * 128 + i * 64) * 8]);
      g2l16(wb + (n0 + row) * 1024 + k0 + kp * 8, &Bs[(w * 128 + i * 64) * 8]);
    }
    __syncthreads();
    bf16x8 af[4], bfr[4];
#pragma unroll
    for (int mt = 0; mt < 4; ++mt)
      af[mt] = *(const bf16x8*)&As[(wm * 64 + mt * 16 + il) * 32 + q * 8];
#pragma unroll
    for (int nt = 0; nt < 4; ++nt)
      bfr[nt] = *(const bf16x8*)&Bs[(wn * 64 + nt * 16 + il) * 32 + q * 8];
#pragma unroll
    for (int mt = 0; mt < 4; ++mt)
#pragma unroll
      for (int nt = 0; nt < 4; ++nt)
        acc[mt][nt] = __builtin_amdgcn_mfma_f32_16x16x32_bf16(af[mt], bfr[nt], acc[mt][nt], 0, 0, 0);
    __syncthreads();
  }

  if (n0 < 3072) {
    // qkv region: plain write, ldc = 3072
#pragma unroll
    for (int nt = 0; nt < 4; ++nt) {
      const long col = n0 + wn * 64 + nt * 16 + il;
#pragma unroll
      for (int mt = 0; mt < 4; ++mt)
#pragma unroll
        for (int r = 0; r < 4; ++r) {
          const long row = m0 + wm * 64 + mt * 16 + q * 4 + r;
          qkv[row * 3072 + col] = f2bf(acc[mt][nt][r]);
        }
    }
  } else {
    // cross region: tanh + row-sum -> atomic into scores (mean scaling done later)
    float rs[16];
#pragma unroll
    for (int j = 0; j < 16; ++j) rs[j] = 0.f;
#pragma unroll
    for (int nt = 0; nt < 4; ++nt) {
      const int col = (int)(n0 - 3072) + wn * 64 + nt * 16 + il;
      const float bv = bcross[col];
#pragma unroll
      for (int mt = 0; mt < 4; ++mt)
#pragma unroll
        for (int r = 0; r < 4; ++r)
          rs[mt * 4 + r] += tanhf(acc[mt][nt][r] + bv);
    }
    // reduce across il (lane bits 0..3 stay within the quad's 16 lanes)
#pragma unroll
    for (int o = 1; o < 16; o <<= 1)
#pragma unroll
      for (int j = 0; j < 16; ++j) rs[j] += __shfl_xor(rs[j], o, 64);
    if (il == 0) {
#pragma unroll
      for (int mt = 0; mt < 4; ++mt)
#pragma unroll
        for (int r = 0; r < 4; ++r) {
          const long row = m0 + wm * 64 + mt * 16 + q * 4 + r;
          atomicAdd(&scores[row], rs[mt * 4 + r]);
        }
    }
  }
}

// C(M,N) = A(M,K;lda) @ B(N,K)^T + bias, fp32 out. XCD-swizzled (gridDim.y%8==0).
__global__ __launch_bounds__(256) void gemm_bt(
    const u16* __restrict__ A, const u16* __restrict__ Bm,
    float* __restrict__ C32, const float* __restrict__ bias,
    int M, int N, int K, int lda)
{
  __shared__ u16 As[128 * 32];
  __shared__ u16 Bs[128 * 32];
  const int tid = threadIdx.x;
  const int lane = tid & 63;
  const int w = tid >> 6;
  const int wm = w >> 1, wn = w & 1;
  const int q = lane >> 4, il = lane & 15;
  const int L = blockIdx.x + blockIdx.y * gridDim.x;
  const int gy8 = gridDim.y >> 3;
  const int kk = L >> 3;
  const int erx = kk / gy8;
  const int ery = (L & 7) + ((kk % gy8) << 3);
  const long m0 = (long)ery * 128, n0 = (long)erx * 128;
  const int ua = w * 128 + lane;

  f32x4 acc[4][4] = {};

  for (int k0 = 0; k0 < K; k0 += 32) {
#pragma unroll
    for (int i = 0; i < 2; ++i) {
      int u = ua + i * 64;
      int row = u >> 2, kp = u & 3;
      g2l16(A + (m0 + row) * (long)lda + k0 + kp * 8, &As[(w * 128 + i * 64) * 8]);
      g2l16(Bm + (n0 + row) * (long)K + k0 + kp * 8, &Bs[(w * 128 + i * 64) * 8]);
    }
    __syncthreads();
    bf16x8 af[4], bfr[4];
#pragma unroll
    for (int mt = 0; mt < 4; ++mt)
      af[mt] = *(const bf16x8*)&As[(wm * 64 + mt * 16 + il) * 32 + q * 8];
#pragma unroll
    for (int nt = 0; nt < 4; ++nt)
      bfr[nt] = *(const bf16x8*)&Bs[(wn * 64 + nt * 16 + il) * 32 + q * 8];
#pragma unroll
    for (int mt = 0; mt < 4; ++mt)
#pragma unroll
      for (int nt = 0; nt < 4; ++nt)
        acc[mt][nt] = __builtin_amdgcn_mfma_f32_16x16x32_bf16(af[mt], bfr[nt], acc[mt][nt], 0, 0, 0);
    __syncthreads();
  }

#pragma unroll
  for (int nt = 0; nt < 4; ++nt) {
    const long col = n0 + wn * 64 + nt * 16 + il;
    const float bv = bias[col];
#pragma unroll
    for (int mt = 0; mt < 4; ++mt)
#pragma unroll
      for (int r = 0; r < 4; ++r) {
        const long row = m0 + wm * 64 + mt * 16 + q * 4 + r;
        C32[row * N + col] = acc[mt][nt][r] + bv;
      }
  }
}

// per-window softmax over scores (sum-of-tanh; scale 1/1024 here) ->
// weighted sum of bf16 x rows -> summaries (fp32)
__global__ __launch_bounds__(256) void summar_k(const u16* __restrict__ xb,
                                                const float* __restrict__ scores,
                                                float* __restrict__ summ)
{
  __shared__ float wts[64];
  const int tid = threadIdx.x;
  const int b = blockIdx.x >> 6, n = blockIdx.x & 63;
  if (tid < 64) {
    float v = scores[(long)b * T_ + n * 64 + tid] * (1.0f / 1024.0f);
    float mx = v;
#pragma unroll
    for (int o = 32; o; o >>= 1) mx = fmaxf(mx, __shfl_xor(mx, o, 64));
    float e = __expf(v - mx);
    float s = e;
#pragma unroll
    for (int o = 32; o; o >>= 1) s += __shfl_xor(s, o, 64);
    wts[tid] = e / s;
  }
  __syncthreads();
  const int d0 = tid * 4;
  const u16* xp = xb + ((long)b * T_ + n * 64) * D_ + d0;
  float a0 = 0, a1 = 0, a2 = 0, a3 = 0;
#pragma unroll 4
  for (int wd = 0; wd < 64; ++wd) {
    uint2 u = *(const uint2*)(xp + (long)wd * D_);
    float wv = wts[wd];
    a0 += wv * b2f((u16)u.x);
    a1 += wv * b2f((u16)(u.x >> 16));
    a2 += wv * b2f((u16)u.y);
    a3 += wv * b2f((u16)(u.y >> 16));
  }
  *(float4*)(summ + ((long)b * NW_ + n) * D_ + d0) = make_float4(a0, a1, a2, a3);
}

// cross-summary attention: cs_out[b,n,:] = softmax(summ[n]·jit[m]/32)_m @ jit
__global__ __launch_bounds__(256) void cross_k(const float* __restrict__ summ,
                                               const int* __restrict__ jitter,
                                               float* __restrict__ cso)
{
  __shared__ float sm[64], pm[64];
  __shared__ int jidx[64];
  const int tid = threadIdx.x;
  const int b = blockIdx.x >> 6, n = blockIdx.x & 63;
  if (tid < 64) jidx[tid] = jitter[tid];
  __syncthreads();
  const int m = tid >> 2, part = tid & 3;
  const float* sn = summ + ((long)b * NW_ + n) * D_;
  const float* sj = summ + ((long)b * NW_ + jidx[m]) * D_;
  float p = 0.f;
  for (int d = part * 256; d < part * 256 + 256; d += 4) {
    float4 aa = *(const float4*)(sn + d);
    float4 bb = *(const float4*)(sj + d);
    p += aa.x * bb.x + aa.y * bb.y + aa.z * bb.z + aa.w * bb.w;
  }
  p += __shfl_xor(p, 1, 64);
  p += __shfl_xor(p, 2, 64);
  if (part == 0) sm[m] = p * (1.0f / 32.0f);
  __syncthreads();
  if (tid < 64) {
    float v = sm[tid], mx = v;
#pragma unroll
    for (int o = 32; o; o >>= 1) mx = fmaxf(mx, __shfl_xor(mx, o, 64));
    float e = __expf(v - mx), s = e;
#pragma unroll
    for (int o = 32; o; o >>= 1) s += __shfl_xor(s, o, 64);
    pm[tid] = e / s;
  }
  __syncthreads();
  const int d0 = tid * 4;
  float a0 = 0, a1 = 0, a2 = 0, a3 = 0;
  for (int mm = 0; mm < 64; ++mm) {
    const float* sr = summ + ((long)b * NW_ + jidx[mm]) * D_ + d0;
    float wv = pm[mm];
    float4 vv = *(const float4*)sr;
    a0 += wv * vv.x; a1 += wv * vv.y; a2 += wv * vv.z; a3 += wv * vv.w;
  }
  *(float4*)(cso + ((long)b * NW_ + n) * D_ + d0) = make_float4(a0, a1, a2, a3);
}

// windowed attention, one block per (b,h,n); writes final = local + 0.25*cs
// IN-PLACE into the q-slice of qkv (each block writes only the region it reads).
__global__ __launch_bounds__(256) void attn_win(u16* qkv,
                                                const float* __restrict__ cso)
{
  __shared__ u16 Qs[64 * 72], Ks[64 * 72], Vt[64 * 72], Ps[64 * 72];
  unsigned* Vt32 = (unsigned*)Vt;          // word stride 36/row (byte 144)
  const int tid = threadIdx.x;
  const int lane = tid & 63;
  const int w = tid >> 6;
  const int q = lane >> 4, il = lane & 15;
  const int bid = blockIdx.x;
  const int n = bid & 63;
  const int h = (bid >> 6) & 15;
  const int b = bid >> 10;
  const long rowbase = (long)b * T_ + n * 64;

#pragma unroll
  for (int i = 0; i < 2; ++i) {
    int u = i * 256 + tid;
    int row = u >> 3, cp = u & 7;
    const u16* src = qkv + (rowbase + row) * 3072 + h * 64 + cp * 8;
    uint4 qv = *(const uint4*)src;
    uint4 kv = *(const uint4*)(src + 1024);
    uint4 vv = *(const uint4*)(src + 2048);
    *(uint4*)&Qs[row * 72 + cp * 8] = qv;
    *(uint4*)&Ks[row * 72 + cp * 8] = kv;
    union { uint4 v; unsigned u[4]; } mine, part;
    mine.v = vv;
#pragma unroll
    for (int m = 0; m < 4; ++m) part.u[m] = __shfl_xor(mine.u[m], 8, 64);
    const bool even = ((row & 1) == 0);
    const int p = row >> 1;
#pragma unroll
    for (int m = 0; m < 4; ++m) {
      unsigned word = even ? ((mine.u[m] & 0xffffu) | (part.u[m] << 16))
                           : ((part.u[m] >> 16)     | (mine.u[m] & 0xffff0000u));
      int c = cp * 8 + 2 * m + (even ? 0 : 1);
      Vt32[c * 36 + p] = word;
    }
  }
  __syncthreads();

  f32x4 sacc[4] = {};
#pragma unroll
  for (int ks = 0; ks < 2; ++ks) {
    bf16x8 aq = *(const bf16x8*)&Qs[(w * 16 + il) * 72 + ks * 32 + q * 8];
#pragma unroll
    for (int ct = 0; ct < 4; ++ct) {
      bf16x8 bk = *(const bf16x8*)&Ks[(ct * 16 + il) * 72 + ks * 32 + q * 8];
      sacc[ct] = __builtin_amdgcn_mfma_f32_16x16x32_bf16(aq, bk, sacc[ct], 0, 0, 0);
    }
  }

#pragma unroll
  for (int r = 0; r < 4; ++r) {
    float s0 = sacc[0][r] * 0.125f, s1 = sacc[1][r] * 0.125f,
          s2 = sacc[2][r] * 0.125f, s3 = sacc[3][r] * 0.125f;
    float mx = fmaxf(fmaxf(s0, s1), fmaxf(s2, s3));
#pragma unroll
    for (int o = 1; o < 16; o <<= 1) mx = fmaxf(mx, __shfl_xor(mx, o, 64));
    float e0 = __expf(s0 - mx), e1 = __expf(s1 - mx),
          e2 = __expf(s2 - mx), e3 = __expf(s3 - mx);
    float sum = e0 + e1 + e2 + e3;
#pragma unroll
    for (int o = 1; o < 16; o <<= 1) sum += __shfl_xor(sum, o, 64);
    float inv = 1.0f / sum;
    int prow = w * 16 + q * 4 + r;
    Ps[prow * 72 + 0 * 16 + il] = f2bf(e0 * inv);
    Ps[prow * 72 + 1 * 16 + il] = f2bf(e1 * inv);
    Ps[prow * 72 + 2 * 16 + il] = f2bf(e2 * inv);
    Ps[prow * 72 + 3 * 16 + il] = f2bf(e3 * inv);
  }
  __syncthreads();

  f32x4 oacc[4] = {};
#pragma unroll
  for (int ks = 0; ks < 2; ++ks) {
    bf16x8 ap = *(const bf16x8*)&Ps[(w * 16 + il) * 72 + ks * 32 + q * 8];
#pragma unroll
    for (int dt = 0; dt < 4; ++dt) {
      bf16x8 bv = *(const bf16x8*)&Vt[(dt * 16 + il) * 72 + ks * 32 + q * 8];
      oacc[dt] = __builtin_amdgcn_mfma_f32_16x16x32_bf16(ap, bv, oacc[dt], 0, 0, 0);
    }
  }

  const float* cs = cso + ((long)b * NW_ + n) * D_ + h * 64;
#pragma unroll
  for (int dt = 0; dt < 4; ++dt) {
    int col = dt * 16 + il;
    float cadd = 0.25f * cs[col];
#pragma unroll
    for (int r = 0; r < 4; ++r) {
      int row = w * 16 + q * 4 + r;
      qkv[(rowbase + row) * 3072 + h * 64 + col] = f2bf(oacc[dt][r] + cadd);
    }
  }
}

extern "C" void kernel_launch(void* const* d_in, const int* in_sizes, int n_in,
                              void* d_out, int out_size, void* d_ws, size_t ws_size,
                              hipStream_t stream)
{
  (void)in_sizes; (void)n_in; (void)out_size; (void)ws_size;
  const float* x      = (const float*)d_in[0];
  const float* Wqkv   = (const float*)d_in[1];
  const float* Wout   = (const float*)d_in[2];
  const float* bout   = (const float*)d_in[3];
  const float* Wcross = (const float*)d_in[4];
  const float* bcross = (const float*)d_in[5];
  const int*   jitter = (const int*)d_in[6];
  float* out = (float*)d_out;

  // ws layout (bytes), total 144,769,024 (identical to passing rounds 3/4):
  //   qkv    @ 0           : 16384x3072 bf16 = 100,663,296
  //   xb     @ 100,663,296 : 16384x1024 bf16 =  33,554,432
  //   wb     @ 134,217,728 : 4096x1024 bf16  =   8,388,608  (Wqkv rows 0-3071, Wcross 3072-4095)
  //   scores @ 142,606,336 : 16384 f32       =      65,536
  //   summ   @ 142,671,872 : 4x64x1024 f32   =   1,048,576
  //   cso    @ 143,720,448 : 4x64x1024 f32   =   1,048,576
  //   wtmp aliases summ+cso (written only after attn_win has consumed cso)
  char* ws = (char*)d_ws;
  u16*   qkv    = (u16*)ws;
  u16*   xb     = (u16*)(ws + 100663296);
  u16*   wb     = (u16*)(ws + 134217728);
  float* scores = (float*)(ws + 142606336);
  float* summ   = (float*)(ws + 142671872);
  float* cso    = (float*)(ws + 143720448);
  u16*   wtmp   = (u16*)(ws + 142671872);

  dim3 blk(256);
  cvt3_k<<<20496, blk, 0, stream>>>(x, xb, Wqkv, Wcross, wb, scores);
  gemm_x<<<dim3(32, 128), blk, 0, stream>>>(xb, wb, qkv, scores, bcross);
  summar_k<<<256, blk, 0, stream>>>(xb, scores, summ);
  cross_k<<<256, blk, 0, stream>>>(summ, jitter, cso);
  attn_win<<<4096, blk, 0, stream>>>(qkv, cso);            // in-place -> q-slice
  cvt_k<<<1024, blk, 0, stream>>>(Wout, wtmp, 1048576L);   // wtmp over summ/cso (both dead)
  gemm_bt<<<dim3(8, 128), blk, 0, stream>>>(qkv, wtmp, out, bout, 16384, 1024, 1024, 3072);
}